// Round 5
// baseline (159.090 us; speedup 1.0000x reference)
//
#include <hip/hip_runtime.h>

// ChannelAttention fused kernel for MI355X (gfx950), round 9.
// B=4, L=16384, C=128, H=8, hd=16. Tokens M = 65536.
//
// R9: kernel split. R8 post-mortem: software pipelining bought 0 (spill
// confounded: +46MB scratch traffic; VGPR_Count=64 misleads, acc lives in
// AGPRs -> ~112 unified in R7 already). VALUBusy 35% re-modeled: exp2 is
// quarter-rate (~8cyc/wave64 issue), true issue floor ~20us, stalls ~65%
// and invariant under barriers/occupancy/ILP. Untested axis: structural
// decoupling of the projection from the long-latency attn kernel.
//   kernel 1 (qkv_attn): stage A (m-split, 3-wide weight batches, peak
//     ~95 regs) + wave-private transpose + attention; o -> global bf16
//     in d_ws. ZERO barriers, LDS 24832 B, __launch_bounds__(256,5)
//     -> 5 blocks/CU, 62.5% occupancy cap, waves fully independent.
//   kernel 2 (proj_out): out = o @ WprojT + b. No LDS, no barrier,
//     2 n x 2 m per wave, HBM/L3-bound ~10us.
// o roundtrip = +34MB traffic (~5us) traded for decoupling. Host falls
// back to the proven R7 fused kernel if ws_size too small.
// Math path bit-identical (fp32 LDS, bf16 o, exp2 softmax) -> absmax same.

typedef __attribute__((ext_vector_type(8))) short bf16x8;
typedef __attribute__((ext_vector_type(4))) float f32x4;
typedef __attribute__((ext_vector_type(4))) unsigned int u32x4;

#define TILE_M 32
#define HALF_M 16
#define QKV_STRIDE_F 388   // fp32 elems per token row (>=384; %8==4 -> 16B aligned rows, spread banks)
#define O_STRIDE 136       // bf16 elems per o row (fallback kernel only)

__device__ __forceinline__ unsigned short f2bf(float f) {
    unsigned int u = __builtin_bit_cast(unsigned int, f);
    u += 0x8000u;                      // round half up (cheap, <=0.5 ulp + tie bias)
    return (unsigned short)(u >> 16);
}
// pack two floats -> packed bf16x2 (lo in low short) in 3 VALU ops
__device__ __forceinline__ unsigned int pkbf(float lo, float hi) {
    unsigned int a = __builtin_bit_cast(unsigned int, lo) + 0x8000u;
    unsigned int b = __builtin_bit_cast(unsigned int, hi) + 0x8000u;
    return __builtin_amdgcn_perm(b, a, 0x07060302u);  // {hi16(b),hi16(a)}
}

__global__ void prep_weights(const float* __restrict__ wqkv,
                             const float* __restrict__ wproj,
                             unsigned short* __restrict__ wqkvT,
                             unsigned short* __restrict__ wprojT) {
    int idx = blockIdx.x * 256 + threadIdx.x;
    if (idx < 384 * 128) {               // wqkvT[n][k] = bf16(wqkv[k][n])
        int n = idx >> 7, k = idx & 127;
        wqkvT[idx] = f2bf(wqkv[k * 384 + n]);
    }
    if (idx < 128 * 128) {               // wprojT[n][k] = bf16(wproj[k][n])
        int n = idx >> 7, k = idx & 127;
        wprojT[idx] = f2bf(wproj[k * 128 + n]);
    }
}

// ================= kernel 1: qkv + channel attention, o -> global =================
__global__ __launch_bounds__(256, 5) void qkv_attn(
    const float* __restrict__ x,
    const unsigned short* __restrict__ wqkvT,
    const float* __restrict__ bqkv,
    unsigned short* __restrict__ o)
{
    __shared__ __align__(16) float us_f[HALF_M * QKV_STRIDE_F];   // 24832 B

    const int tid  = threadIdx.x;
    const int lane = tid & 63;
    const int wave = tid >> 6;
    const int col  = lane & 15;
    const int quad = lane >> 4;
    const long base_tok = (long)blockIdx.x * TILE_M;

    // head-aligned n-tiles: wave w produces q,k,v channel tiles of heads 2w, 2w+1
    int ntile[6];
    ntile[0] = 2 * wave;      ntile[1] = 2 * wave + 1;
    ntile[2] = 8 + 2 * wave;  ntile[3] = 9 + 2 * wave;
    ntile[4] = 16 + 2 * wave; ntile[5] = 17 + 2 * wave;

    f32x4 acc[2][6];
    // ---- stage A, m-split to cap live registers (~95 peak):
    // per m: load+pack x frags (16 regs), then 4 ks x {3-wide weight batch, MFMA}
#pragma unroll
    for (int m = 0; m < 2; ++m) {
        const float* xrow = x + (base_tok + m * 16 + col) * 128;
        bf16x8 afr[4];
#pragma unroll
        for (int ks = 0; ks < 4; ++ks) {
            const float4* p = (const float4*)(xrow + ks * 32 + quad * 8);
            float4 f0 = p[0], f1 = p[1];
            u32x4 a = {pkbf(f0.x, f0.y), pkbf(f0.z, f0.w),
                       pkbf(f1.x, f1.y), pkbf(f1.z, f1.w)};
            afr[ks] = __builtin_bit_cast(bf16x8, a);
        }
#pragma unroll
        for (int j = 0; j < 6; ++j) {
            float b = bqkv[ntile[j] * 16 + col];
            acc[m][j] = (f32x4){b, b, b, b};
        }
#pragma unroll
        for (int ks = 0; ks < 4; ++ks) {
#pragma unroll
            for (int jb = 0; jb < 2; ++jb) {       // 3-wide weight batches
                bf16x8 bfr[3];
#pragma unroll
                for (int j = 0; j < 3; ++j)
                    bfr[j] = *(const bf16x8*)&wqkvT[(ntile[jb * 3 + j] * 16 + col) * 128 + ks * 32 + quad * 8];
#pragma unroll
                for (int j = 0; j < 3; ++j)
                    acc[m][jb * 3 + j] = __builtin_amdgcn_mfma_f32_16x16x32_bf16(
                        afr[ks], bfr[j], acc[m][jb * 3 + j], 0, 0, 0);
            }
        }
    }

    // ---- stage B lane roles: (token, head-bit, i-half) within the wave
    const int t    = lane & 15;
    const int hbit = (lane >> 4) & 1;
    const int ih   = lane >> 5;
    const int h    = 2 * wave + hbit;
    const float* qkvrow = us_f + t * QKV_STRIDE_F + h * 16;
    const float sl2e = 0.08838834764831845f * 1.44269504088896340f; // scale*log2(e)

    auto write_half = [&](int m) {
#pragma unroll
        for (int j = 0; j < 6; ++j)
#pragma unroll
            for (int r = 0; r < 4; ++r)
                us_f[(quad * 4 + r) * QKV_STRIDE_F + ntile[j] * 16 + col] = acc[m][j][r];
    };

    float4 qv4[2], kv4[4], vv4[4];   // 10 ds_read_b128 per half
    auto read_half = [&]() {
        qv4[0] = ((const float4*)(qkvrow + ih * 8))[0];
        qv4[1] = ((const float4*)(qkvrow + ih * 8))[1];
#pragma unroll
        for (int c = 0; c < 4; ++c) {
            kv4[c] = ((const float4*)(qkvrow + 128))[c];
            vv4[c] = ((const float4*)(qkvrow + 256))[c];
        }
    };

    auto attn_half = [&](int mhalf) {
        float qv[8], kf[16], vf[16];
#pragma unroll
        for (int c = 0; c < 2; ++c) {
            qv[4*c] = qv4[c].x; qv[4*c+1] = qv4[c].y; qv[4*c+2] = qv4[c].z; qv[4*c+3] = qv4[c].w;
        }
#pragma unroll
        for (int c = 0; c < 4; ++c) {
            kf[4*c] = kv4[c].x; kf[4*c+1] = kv4[c].y; kf[4*c+2] = kv4[c].z; kf[4*c+3] = kv4[c].w;
            vf[4*c] = vv4[c].x; vf[4*c+1] = vv4[c].y; vf[4*c+2] = vv4[c].z; vf[4*c+3] = vv4[c].w;
        }
        float ov[8];
#pragma unroll
        for (int i = 0; i < 8; ++i) {
            float qs = qv[i] * sl2e;
            float den = 0.f, num = 0.f;
#pragma unroll
            for (int j = 0; j < 16; ++j) {
                float e = __builtin_amdgcn_exp2f(qs * kf[j]);
                den += e;
                num = fmaf(e, vf[j], num);
            }
            ov[i] = num * __builtin_amdgcn_rcpf(den);
        }
        u32x4 o0 = {pkbf(ov[0], ov[1]), pkbf(ov[2], ov[3]),
                    pkbf(ov[4], ov[5]), pkbf(ov[6], ov[7])};
        // 16B global store; per token-row this wave covers one 64B chunk
        *(u32x4*)&o[(base_tok + mhalf * 16 + t) * 128 + h * 16 + ih * 8] = o0;
    };

    // ---- zero-barrier wave-private pipeline (R7 invariant: each wave
    // reads/writes only its own columns of us_f)
    write_half(0);
    read_half();           // RAW same wave: in-order DS
    write_half(1);         // anti-dep on reads: program order keeps safe
    attn_half(0);
    read_half();
    attn_half(1);
}

// ================= kernel 2: out = o @ WprojT + b =================
__global__ __launch_bounds__(256) void proj_out(
    const unsigned short* __restrict__ o,
    const unsigned short* __restrict__ wprojT,
    const float* __restrict__ bproj,
    float* __restrict__ out)
{
    const int tid  = threadIdx.x;
    const int lane = tid & 63;
    const int wave = tid >> 6;
    const int col  = lane & 15;
    const int quad = lane >> 4;
    const long base_tok = (long)blockIdx.x * TILE_M;
    const int nb2 = wave * 2;

#pragma unroll
    for (int m = 0; m < 2; ++m) {
        bf16x8 af[4];
#pragma unroll
        for (int ks = 0; ks < 4; ++ks)
            af[ks] = *(const bf16x8*)&o[(base_tok + m * 16 + col) * 128 + ks * 32 + quad * 8];
        f32x4 acc2[2];
#pragma unroll
        for (int n = 0; n < 2; ++n) {
            float b = bproj[(nb2 + n) * 16 + col];
            acc2[n] = (f32x4){b, b, b, b};
        }
#pragma unroll
        for (int ks = 0; ks < 4; ++ks) {
            bf16x8 bb[2];
#pragma unroll
            for (int n = 0; n < 2; ++n)
                bb[n] = *(const bf16x8*)&wprojT[((nb2 + n) * 16 + col) * 128 + ks * 32 + quad * 8];
#pragma unroll
            for (int n = 0; n < 2; ++n)
                acc2[n] = __builtin_amdgcn_mfma_f32_16x16x32_bf16(af[ks], bb[n], acc2[n], 0, 0, 0);
        }
#pragma unroll
        for (int n = 0; n < 2; ++n)
#pragma unroll
            for (int r = 0; r < 4; ++r) {
                long tt = base_tok + m * 16 + quad * 4 + r;
                out[tt * 128 + (nb2 + n) * 16 + col] = acc2[n][r];
            }
    }
}

// ================= fallback: proven R7 fused kernel (ws too small) =================
__global__ __launch_bounds__(256, 4) void fused_channel_attn_fb(
    const float* __restrict__ x,
    const unsigned short* __restrict__ wqkvT,
    const float* __restrict__ bqkv,
    const unsigned short* __restrict__ wprojT,
    const float* __restrict__ bproj,
    float* __restrict__ out)
{
    __shared__ __align__(16) float us_f[HALF_M * QKV_STRIDE_F];
    __shared__ __align__(16) unsigned short us_o[TILE_M * O_STRIDE];

    const int tid  = threadIdx.x;
    const int lane = tid & 63;
    const int wave = tid >> 6;
    const int col  = lane & 15;
    const int quad = lane >> 4;
    const long base_tok = (long)blockIdx.x * TILE_M;

    int ntile[6];
    ntile[0] = 2 * wave;      ntile[1] = 2 * wave + 1;
    ntile[2] = 8 + 2 * wave;  ntile[3] = 9 + 2 * wave;
    ntile[4] = 16 + 2 * wave; ntile[5] = 17 + 2 * wave;

    bf16x8 afr[2][4];
#pragma unroll
    for (int m = 0; m < 2; ++m) {
        const float* xrow = x + (base_tok + m * 16 + col) * 128;
#pragma unroll
        for (int ks = 0; ks < 4; ++ks) {
            const float4* p = (const float4*)(xrow + ks * 32 + quad * 8);
            float4 f0 = p[0], f1 = p[1];
            u32x4 a = {pkbf(f0.x, f0.y), pkbf(f0.z, f0.w),
                       pkbf(f1.x, f1.y), pkbf(f1.z, f1.w)};
            afr[m][ks] = __builtin_bit_cast(bf16x8, a);
        }
    }
    f32x4 acc[2][6];
#pragma unroll
    for (int j = 0; j < 6; ++j) {
        float b = bqkv[ntile[j] * 16 + col];
        acc[0][j] = (f32x4){b, b, b, b};
        acc[1][j] = (f32x4){b, b, b, b};
    }
#pragma unroll
    for (int ks = 0; ks < 4; ++ks) {
        bf16x8 bfr[6];
#pragma unroll
        for (int j = 0; j < 6; ++j)
            bfr[j] = *(const bf16x8*)&wqkvT[(ntile[j] * 16 + col) * 128 + ks * 32 + quad * 8];
#pragma unroll
        for (int j = 0; j < 6; ++j) {
            acc[0][j] = __builtin_amdgcn_mfma_f32_16x16x32_bf16(afr[0][ks], bfr[j], acc[0][j], 0, 0, 0);
            acc[1][j] = __builtin_amdgcn_mfma_f32_16x16x32_bf16(afr[1][ks], bfr[j], acc[1][j], 0, 0, 0);
        }
    }

    const int t    = lane & 15;
    const int hbit = (lane >> 4) & 1;
    const int ih   = lane >> 5;
    const int h    = 2 * wave + hbit;
    const float* qkvrow = us_f + t * QKV_STRIDE_F + h * 16;
    const float sl2e = 0.08838834764831845f * 1.44269504088896340f;

    auto write_half = [&](int m) {
#pragma unroll
        for (int j = 0; j < 6; ++j)
#pragma unroll
            for (int r = 0; r < 4; ++r)
                us_f[(quad * 4 + r) * QKV_STRIDE_F + ntile[j] * 16 + col] = acc[m][j][r];
    };
    float4 qv4[2], kv4[4], vv4[4];
    auto read_half = [&]() {
        qv4[0] = ((const float4*)(qkvrow + ih * 8))[0];
        qv4[1] = ((const float4*)(qkvrow + ih * 8))[1];
#pragma unroll
        for (int c = 0; c < 4; ++c) {
            kv4[c] = ((const float4*)(qkvrow + 128))[c];
            vv4[c] = ((const float4*)(qkvrow + 256))[c];
        }
    };
    auto attn_half = [&](int mhalf) {
        float qv[8], kf[16], vf[16];
#pragma unroll
        for (int c = 0; c < 2; ++c) {
            qv[4*c] = qv4[c].x; qv[4*c+1] = qv4[c].y; qv[4*c+2] = qv4[c].z; qv[4*c+3] = qv4[c].w;
        }
#pragma unroll
        for (int c = 0; c < 4; ++c) {
            kf[4*c] = kv4[c].x; kf[4*c+1] = kv4[c].y; kf[4*c+2] = kv4[c].z; kf[4*c+3] = kv4[c].w;
            vf[4*c] = vv4[c].x; vf[4*c+1] = vv4[c].y; vf[4*c+2] = vv4[c].z; vf[4*c+3] = vv4[c].w;
        }
        float ov[8];
#pragma unroll
        for (int i = 0; i < 8; ++i) {
            float qs = qv[i] * sl2e;
            float den = 0.f, num = 0.f;
#pragma unroll
            for (int j = 0; j < 16; ++j) {
                float e = __builtin_amdgcn_exp2f(qs * kf[j]);
                den += e;
                num = fmaf(e, vf[j], num);
            }
            ov[i] = num * __builtin_amdgcn_rcpf(den);
        }
        u32x4 o0 = {pkbf(ov[0], ov[1]), pkbf(ov[2], ov[3]),
                    pkbf(ov[4], ov[5]), pkbf(ov[6], ov[7])};
        *(u32x4*)&us_o[(mhalf * 16 + t) * O_STRIDE + h * 16 + ih * 8] = o0;
    };

    write_half(0);
    read_half();
    write_half(1);
    attn_half(0);
    read_half();
    attn_half(1);

    __syncthreads();

    const int nb2 = wave * 2;
#pragma unroll
    for (int m = 0; m < 2; ++m) {
        bf16x8 af[4];
#pragma unroll
        for (int ks = 0; ks < 4; ++ks)
            af[ks] = *(const bf16x8*)&us_o[(m * 16 + col) * O_STRIDE + ks * 32 + quad * 8];
        f32x4 acc2[2];
#pragma unroll
        for (int n = 0; n < 2; ++n) {
            float b = bproj[(nb2 + n) * 16 + col];
            acc2[n] = (f32x4){b, b, b, b};
        }
#pragma unroll
        for (int ks = 0; ks < 4; ++ks) {
            bf16x8 bb[2];
#pragma unroll
            for (int n = 0; n < 2; ++n)
                bb[n] = *(const bf16x8*)&wprojT[((nb2 + n) * 16 + col) * 128 + ks * 32 + quad * 8];
#pragma unroll
            for (int n = 0; n < 2; ++n)
                acc2[n] = __builtin_amdgcn_mfma_f32_16x16x32_bf16(af[ks], bb[n], acc2[n], 0, 0, 0);
        }
#pragma unroll
        for (int n = 0; n < 2; ++n)
#pragma unroll
            for (int r = 0; r < 4; ++r) {
                long tt = base_tok + m * 16 + quad * 4 + r;
                out[tt * 128 + (nb2 + n) * 16 + col] = acc2[n][r];
            }
    }
}

extern "C" void kernel_launch(void* const* d_in, const int* in_sizes, int n_in,
                              void* d_out, int out_size, void* d_ws, size_t ws_size,
                              hipStream_t stream) {
    const float* x     = (const float*)d_in[0];
    const float* wqkv  = (const float*)d_in[1];
    const float* bqkv  = (const float*)d_in[2];
    const float* wproj = (const float*)d_in[3];
    const float* bproj = (const float*)d_in[4];
    float* out = (float*)d_out;

    unsigned short* wqkvT  = (unsigned short*)d_ws;    // 384*128 bf16
    unsigned short* wprojT = wqkvT + 384 * 128;        // 128*128 bf16
    unsigned short* o      = wprojT + 128 * 128;       // 65536*128 bf16 (split path)

    prep_weights<<<192, 256, 0, stream>>>(wqkv, wproj, wqkvT, wprojT);

    const int tokens = in_sizes[0] / 128;              // 65536
    const size_t ws_needed = (size_t)(384 + 128) * 128 * 2 + (size_t)tokens * 128 * 2;

    if (ws_size >= ws_needed) {
        qkv_attn<<<tokens / TILE_M, 256, 0, stream>>>(x, wqkvT, bqkv, o);
        proj_out<<<tokens / TILE_M, 256, 0, stream>>>(o, wprojT, bproj, out);
    } else {
        fused_channel_attn_fb<<<tokens / TILE_M, 256, 0, stream>>>(
            x, wqkvT, bqkv, wprojT, bproj, out);
    }
}

// Round 7
// 132.799 us; speedup vs baseline: 1.1980x; 1.1980x over previous
//
#include <hip/hip_runtime.h>

// ChannelAttention fused kernel for MI355X (gfx950), round 11.
// B=4, L=16384, C=128, H=8, hd=16. Tokens M = 65536.
//
// R11 = R7 base (proven 58.5us/dispatch, absmax 0.0078: fused, head-aligned
// wave-private qkv transpose, 1 barrier, (256,4), no spill) with ONE change:
// exp2 computed on the full-rate VALU instead of the quarter-rate TRANS pipe.
//
// Why: R4-R9 invariant: VALUBusy*dur ~= 49K cycles/SIMD across barriers
// 4->1->0, occupancy 26->41%, pipelining, kernel split; dur pinned 58-66us
// vs ~15-20us issue floor. Every scheduling lever failed. The untested
// resource is TRANS itself: 256 v_exp_f32/thread at quarter rate is the
// single largest issue block and its contention is invisible in VALUBusy.
// R10's packed-VOP3P asm FAILED correctness (op_sel_hi semantics) - dropped.
//
// exp2_poly: n = round-to-nearest via 1.5*2^23 magic add (exact for |x|<2^22);
// f = x - n in [-0.5,0.5]; 2^f = deg-4 Taylor (rel err <= 4.3e-5, ~20x under
// the bf16 quantum that sets absmax); scale by 2^n via integer exponent add
// on the bitcast (n<<23 == bitcast(magic+n)<<23, low 9 bits of 0x4B400000
// are zero; poly in [0.7,1.42] and |n|<=~8 -> no denormal/overflow).
// 9 full-rate VALU ops, zero TRANS.
//
// Pre-committed readout:
//   TRANS-contended: dur -> 40-46us, VALUBusy up to 50-65%  -> keep, iterate
//   issue-coupled:   dur -> 64-72us, VALUBusy up to 40-50%  -> revert to R7
//   I$-bound:        dur -> 70-90us, VALUBusy DOWN <30%     -> shrink code
//   neither:         dur flat 58-62                          -> lock R7
// Guards: FETCH ~17MB WRITE ~33MB (no spill), VGPR <= ~80, absmax <= ~0.01.

typedef __attribute__((ext_vector_type(8))) short bf16x8;
typedef __attribute__((ext_vector_type(4))) float f32x4;
typedef __attribute__((ext_vector_type(4))) unsigned int u32x4;

#define TILE_M 32
#define HALF_M 16
#define QKV_STRIDE_F 388   // fp32 elems per token row (>=384; %8==4 -> 16B aligned rows, spread banks)
#define O_STRIDE 136       // bf16 elems per o row

__device__ __forceinline__ unsigned short f2bf(float f) {
    unsigned int u = __builtin_bit_cast(unsigned int, f);
    u += 0x8000u;                      // round half up (cheap, <=0.5 ulp + tie bias)
    return (unsigned short)(u >> 16);
}
// pack two floats -> packed bf16x2 (lo in low short) in 3 VALU ops
__device__ __forceinline__ unsigned int pkbf(float lo, float hi) {
    unsigned int a = __builtin_bit_cast(unsigned int, lo) + 0x8000u;
    unsigned int b = __builtin_bit_cast(unsigned int, hi) + 0x8000u;
    return __builtin_amdgcn_perm(b, a, 0x07060302u);  // {hi16(b),hi16(a)}
}

// Full-rate-VALU exp2 (no TRANS). 9 ops: add,sub,sub,lshl,4xfma,add.
// Valid for |x| < ~60 (here |x| <= ~5). Rel err <= 4.3e-5 on f in [-.5,.5].
__device__ __forceinline__ float exp2_poly(float xx) {
    const float MAGIC = 12582912.0f;   // 1.5 * 2^23
    float fm = xx + MAGIC;             // round-to-nearest lands in mantissa
    float nf = fm - MAGIC;             // n as float (exact)
    float f  = xx - nf;                // f in [-0.5, 0.5]
    unsigned int t = __builtin_bit_cast(unsigned int, fm) << 23;  // == n << 23
    float p = fmaf(f, 0.0096181291f, 0.0555041087f);   // ln2^4/24, ln2^3/6
    p = fmaf(f, p, 0.2402265069f);                     // ln2^2/2
    p = fmaf(f, p, 0.6931471806f);                     // ln2
    p = fmaf(f, p, 1.0f);
    return __builtin_bit_cast(float, __builtin_bit_cast(unsigned int, p) + t);
}

__global__ void prep_weights(const float* __restrict__ wqkv,
                             const float* __restrict__ wproj,
                             unsigned short* __restrict__ wqkvT,
                             unsigned short* __restrict__ wprojT) {
    int idx = blockIdx.x * 256 + threadIdx.x;
    if (idx < 384 * 128) {               // wqkvT[n][k] = bf16(wqkv[k][n])
        int n = idx >> 7, k = idx & 127;
        wqkvT[idx] = f2bf(wqkv[k * 384 + n]);
    }
    if (idx < 128 * 128) {               // wprojT[n][k] = bf16(wproj[k][n])
        int n = idx >> 7, k = idx & 127;
        wprojT[idx] = f2bf(wproj[k * 128 + n]);
    }
}

__global__ __launch_bounds__(256, 4) void fused_channel_attn(
    const float* __restrict__ x,
    const unsigned short* __restrict__ wqkvT,
    const float* __restrict__ bqkv,
    const unsigned short* __restrict__ wprojT,
    const float* __restrict__ bproj,
    float* __restrict__ out)
{
    __shared__ __align__(16) float us_f[HALF_M * QKV_STRIDE_F];        // 24832 B, half-tile qkv fp32
    __shared__ __align__(16) unsigned short us_o[TILE_M * O_STRIDE];   // 8704 B, full-tile o bf16

    const int tid  = threadIdx.x;
    const int lane = tid & 63;
    const int wave = tid >> 6;
    const int col  = lane & 15;   // MFMA C/D col == A row (m) == B col (n)
    const int quad = lane >> 4;
    const long base_tok = (long)blockIdx.x * TILE_M;

    // head-aligned n-tiles: wave w produces q,k,v channel tiles of heads 2w, 2w+1
    int ntile[6];
    ntile[0] = 2 * wave;      ntile[1] = 2 * wave + 1;
    ntile[2] = 8 + 2 * wave;  ntile[3] = 9 + 2 * wave;
    ntile[4] = 16 + 2 * wave; ntile[5] = 17 + 2 * wave;

    // ---- stage A: x fragments, load+pack fused per (m,ks)
    bf16x8 afr[2][4];
#pragma unroll
    for (int m = 0; m < 2; ++m) {
        const float* xrow = x + (base_tok + m * 16 + col) * 128;
#pragma unroll
        for (int ks = 0; ks < 4; ++ks) {
            const float4* p = (const float4*)(xrow + ks * 32 + quad * 8);
            float4 f0 = p[0], f1 = p[1];
            u32x4 a = {pkbf(f0.x, f0.y), pkbf(f0.z, f0.w),
                       pkbf(f1.x, f1.y), pkbf(f1.z, f1.w)};
            afr[m][ks] = __builtin_bit_cast(bf16x8, a);
        }
    }

    // acc[m][j][r] = qkv[m*16 + quad*4 + r][ntile[j]*16 + col]; init = bias
    f32x4 acc[2][6];
#pragma unroll
    for (int j = 0; j < 6; ++j) {
        float b = bqkv[ntile[j] * 16 + col];
        acc[0][j] = (f32x4){b, b, b, b};
        acc[1][j] = (f32x4){b, b, b, b};
    }
#pragma unroll
    for (int ks = 0; ks < 4; ++ks) {
        bf16x8 bfr[6];                 // batched: 6 loads in flight
#pragma unroll
        for (int j = 0; j < 6; ++j)
            bfr[j] = *(const bf16x8*)&wqkvT[(ntile[j] * 16 + col) * 128 + ks * 32 + quad * 8];
#pragma unroll
        for (int j = 0; j < 6; ++j) {  // each bfrag feeds 2 MFMAs
            acc[0][j] = __builtin_amdgcn_mfma_f32_16x16x32_bf16(afr[0][ks], bfr[j], acc[0][j], 0, 0, 0);
            acc[1][j] = __builtin_amdgcn_mfma_f32_16x16x32_bf16(afr[1][ks], bfr[j], acc[1][j], 0, 0, 0);
        }
    }

    // ---- stage B lane roles: (token, head-bit, i-half) within the wave
    const int t    = lane & 15;
    const int hbit = (lane >> 4) & 1;
    const int ih   = lane >> 5;
    const int h    = 2 * wave + hbit;           // head owned by this lane
    const float* qkvrow = us_f + t * QKV_STRIDE_F + h * 16;
    const float sl2e = 0.08838834764831845f * 1.44269504088896340f; // scale*log2(e)

    // write one 16-token half of this wave's qkv columns -> LDS fp32 [tok][ch]
    auto write_half = [&](int m) {
#pragma unroll
        for (int j = 0; j < 6; ++j)
#pragma unroll
            for (int r = 0; r < 4; ++r)
                us_f[(quad * 4 + r) * QKV_STRIDE_F + ntile[j] * 16 + col] = acc[m][j][r];
    };

    float4 qv4[2], kv4[4], vv4[4];   // 10 ds_read_b128 per half
    auto read_half = [&]() {
        qv4[0] = ((const float4*)(qkvrow + ih * 8))[0];
        qv4[1] = ((const float4*)(qkvrow + ih * 8))[1];
#pragma unroll
        for (int c = 0; c < 4; ++c) {
            kv4[c] = ((const float4*)(qkvrow + 128))[c];
            vv4[c] = ((const float4*)(qkvrow + 256))[c];
        }
    };

    auto attn_half = [&](int mhalf) {
        float qv[8], kf[16], vf[16];
#pragma unroll
        for (int c = 0; c < 2; ++c) {
            qv[4*c] = qv4[c].x; qv[4*c+1] = qv4[c].y; qv[4*c+2] = qv4[c].z; qv[4*c+3] = qv4[c].w;
        }
#pragma unroll
        for (int c = 0; c < 4; ++c) {
            kf[4*c] = kv4[c].x; kf[4*c+1] = kv4[c].y; kf[4*c+2] = kv4[c].z; kf[4*c+3] = kv4[c].w;
            vf[4*c] = vv4[c].x; vf[4*c+1] = vv4[c].y; vf[4*c+2] = vv4[c].z; vf[4*c+3] = vv4[c].w;
        }
        float ov[8];
#pragma unroll
        for (int i = 0; i < 8; ++i) {
            float qs = qv[i] * sl2e;
            float den = 0.f, num = 0.f;
#pragma unroll
            for (int j = 0; j < 16; ++j) {
                float e = exp2_poly(qs * kf[j]);   // full-rate VALU, no TRANS
                den += e;
                num = fmaf(e, vf[j], num);
            }
            ov[i] = num * __builtin_amdgcn_rcpf(den);
        }
        u32x4 o0 = {pkbf(ov[0], ov[1]), pkbf(ov[2], ov[3]),
                    pkbf(ov[4], ov[5]), pkbf(ov[6], ov[7])};
        *(u32x4*)&us_o[(mhalf * 16 + t) * O_STRIDE + h * 16 + ih * 8] = o0;  // b128, A-layout
    };

    // ---- barrier-free wave-private qkv pipeline (R7)
    write_half(0);         // 24 ds_write_b32 (wave-owned columns only)
    read_half();           // RAW same wave: compiler lgkmcnt, in-order DS
    write_half(1);         // anti-dep on reads: program order keeps safe;
                           // latency hides under half-0 exp burst below
    attn_half(0);
    read_half();           // RAW on half-1 writes (same wave)
    attn_half(1);

    __syncthreads();       // the ONE barrier: o (all heads/waves) -> stage C

    // ---- stage C: out = o @ Wproj + b. Wave: 2 n-tiles x 2 m-tiles.
    const int nb2 = wave * 2;
#pragma unroll
    for (int m = 0; m < 2; ++m) {
        bf16x8 af[4];
#pragma unroll
        for (int ks = 0; ks < 4; ++ks)
            af[ks] = *(const bf16x8*)&us_o[(m * 16 + col) * O_STRIDE + ks * 32 + quad * 8];
        f32x4 acc2[2];
#pragma unroll
        for (int n = 0; n < 2; ++n) {
            float b = bproj[(nb2 + n) * 16 + col];
            acc2[n] = (f32x4){b, b, b, b};
        }
#pragma unroll
        for (int ks = 0; ks < 4; ++ks) {
            bf16x8 bb[2];
#pragma unroll
            for (int n = 0; n < 2; ++n)
                bb[n] = *(const bf16x8*)&wprojT[((nb2 + n) * 16 + col) * 128 + ks * 32 + quad * 8];
#pragma unroll
            for (int n = 0; n < 2; ++n)
                acc2[n] = __builtin_amdgcn_mfma_f32_16x16x32_bf16(af[ks], bb[n], acc2[n], 0, 0, 0);
        }
#pragma unroll
        for (int n = 0; n < 2; ++n)
#pragma unroll
            for (int r = 0; r < 4; ++r) {
                long tt = base_tok + m * 16 + quad * 4 + r;
                out[tt * 128 + (nb2 + n) * 16 + col] = acc2[n][r];
            }
    }
}

extern "C" void kernel_launch(void* const* d_in, const int* in_sizes, int n_in,
                              void* d_out, int out_size, void* d_ws, size_t ws_size,
                              hipStream_t stream) {
    const float* x     = (const float*)d_in[0];
    const float* wqkv  = (const float*)d_in[1];
    const float* bqkv  = (const float*)d_in[2];
    const float* wproj = (const float*)d_in[3];
    const float* bproj = (const float*)d_in[4];
    float* out = (float*)d_out;

    unsigned short* wqkvT  = (unsigned short*)d_ws;    // 384*128 bf16
    unsigned short* wprojT = wqkvT + 384 * 128;        // 128*128 bf16

    prep_weights<<<192, 256, 0, stream>>>(wqkv, wproj, wqkvT, wprojT);

    const int tokens = in_sizes[0] / 128;              // 65536
    fused_channel_attn<<<tokens / TILE_M, 256, 0, stream>>>(
        x, wqkvT, bqkv, wprojT, bproj, out);
}

// Round 8
// 131.879 us; speedup vs baseline: 1.2063x; 1.0070x over previous
//
#include <hip/hip_runtime.h>

// ChannelAttention fused kernel for MI355X (gfx950), round 12.
// B=4, L=16384, C=128, H=8, hd=16. Tokens M = 65536.
//
// R12 = R7 base with ONE change: stage B's i-loop is ROLLED (4 iters x
// 2 channels) to shrink code ~14KB -> ~6-7KB. I$-thrash test.
//
// Why: R4-R11 invariants: dur pinned 58-66us while VALUBusy 30->60%
// (R11 added ~70% more VALU instrs -> busy +25pts, dur FLAT: issue port
// has huge slack), occupancy 26->41%, barriers 4->1->0, TRANS swapped
// out, kernel split, pipelining - nothing moves dur. No pipe saturated,
// waves hold runnable work but SIMDs idle >50%: instruction DELIVERY is
// throttled. Never varied/measured: I$. Fully-unrolled stage B is ~10KB;
// 3-4 blocks/CU at staggered progress stream ~14KB each through the
// 32KB shared I$ -> thrash. Fits: R11's 2x footprint was slightly
// WORSE; de-phasing never helped (de-phased waves thrash more).
//
// Rolled-loop details (rule: no runtime-indexed private arrays):
//   - q re-read from LDS per iteration (qkvrow[ih*8+ip*2+u]) instead of
//     held in qv[8]; k/v stay as compile-time float4 components.
//   - o packed per pair, ds_write_b32 at runtime address (fine).
//   - attn_half(0) moved BEFORE write_half(1) so lazy q reads see half-0
//     (wave-private, program order -> safe). Same values, same summation
//     order -> bit-identical, absmax must be exactly 0.0078125.
//   - back to v_exp_f32 (1 instr; R11 proved TRANS<->VALU is perf-neutral,
//     so take the small-code variant).
//
// Pre-committed readout:
//   I$-thrash:  dur -> 35-45us, VALUBusy ~35-45%   -> keep, iterate on size
//   flat 55-62: I$ dead -> R13 attacks occupancy via bf16 LDS staging
// Guards: FETCH ~17MB WRITE ~33MB, VGPR <= 64, LDS 33792, absmax 0.0078125.

typedef __attribute__((ext_vector_type(8))) short bf16x8;
typedef __attribute__((ext_vector_type(4))) float f32x4;
typedef __attribute__((ext_vector_type(4))) unsigned int u32x4;

#define TILE_M 32
#define HALF_M 16
#define QKV_STRIDE_F 388   // fp32 elems per token row (>=384; %8==4 -> 16B aligned rows, spread banks)
#define O_STRIDE 136       // bf16 elems per o row

__device__ __forceinline__ unsigned short f2bf(float f) {
    unsigned int u = __builtin_bit_cast(unsigned int, f);
    u += 0x8000u;                      // round half up (cheap, <=0.5 ulp + tie bias)
    return (unsigned short)(u >> 16);
}
// pack two floats -> packed bf16x2 (lo in low short) in 3 VALU ops
__device__ __forceinline__ unsigned int pkbf(float lo, float hi) {
    unsigned int a = __builtin_bit_cast(unsigned int, lo) + 0x8000u;
    unsigned int b = __builtin_bit_cast(unsigned int, hi) + 0x8000u;
    return __builtin_amdgcn_perm(b, a, 0x07060302u);  // {hi16(b),hi16(a)}
}

__global__ void prep_weights(const float* __restrict__ wqkv,
                             const float* __restrict__ wproj,
                             unsigned short* __restrict__ wqkvT,
                             unsigned short* __restrict__ wprojT) {
    int idx = blockIdx.x * 256 + threadIdx.x;
    if (idx < 384 * 128) {               // wqkvT[n][k] = bf16(wqkv[k][n])
        int n = idx >> 7, k = idx & 127;
        wqkvT[idx] = f2bf(wqkv[k * 384 + n]);
    }
    if (idx < 128 * 128) {               // wprojT[n][k] = bf16(wproj[k][n])
        int n = idx >> 7, k = idx & 127;
        wprojT[idx] = f2bf(wproj[k * 128 + n]);
    }
}

__global__ __launch_bounds__(256, 4) void fused_channel_attn(
    const float* __restrict__ x,
    const unsigned short* __restrict__ wqkvT,
    const float* __restrict__ bqkv,
    const unsigned short* __restrict__ wprojT,
    const float* __restrict__ bproj,
    float* __restrict__ out)
{
    __shared__ __align__(16) float us_f[HALF_M * QKV_STRIDE_F];        // 24832 B, half-tile qkv fp32
    __shared__ __align__(16) unsigned short us_o[TILE_M * O_STRIDE];   // 8704 B, full-tile o bf16

    const int tid  = threadIdx.x;
    const int lane = tid & 63;
    const int wave = tid >> 6;
    const int col  = lane & 15;   // MFMA C/D col == A row (m) == B col (n)
    const int quad = lane >> 4;
    const long base_tok = (long)blockIdx.x * TILE_M;

    // head-aligned n-tiles: wave w produces q,k,v channel tiles of heads 2w, 2w+1
    int ntile[6];
    ntile[0] = 2 * wave;      ntile[1] = 2 * wave + 1;
    ntile[2] = 8 + 2 * wave;  ntile[3] = 9 + 2 * wave;
    ntile[4] = 16 + 2 * wave; ntile[5] = 17 + 2 * wave;

    // ---- stage A: x fragments, load+pack fused per (m,ks)
    bf16x8 afr[2][4];
#pragma unroll
    for (int m = 0; m < 2; ++m) {
        const float* xrow = x + (base_tok + m * 16 + col) * 128;
#pragma unroll
        for (int ks = 0; ks < 4; ++ks) {
            const float4* p = (const float4*)(xrow + ks * 32 + quad * 8);
            float4 f0 = p[0], f1 = p[1];
            u32x4 a = {pkbf(f0.x, f0.y), pkbf(f0.z, f0.w),
                       pkbf(f1.x, f1.y), pkbf(f1.z, f1.w)};
            afr[m][ks] = __builtin_bit_cast(bf16x8, a);
        }
    }

    // acc[m][j][r] = qkv[m*16 + quad*4 + r][ntile[j]*16 + col]; init = bias
    f32x4 acc[2][6];
#pragma unroll
    for (int j = 0; j < 6; ++j) {
        float b = bqkv[ntile[j] * 16 + col];
        acc[0][j] = (f32x4){b, b, b, b};
        acc[1][j] = (f32x4){b, b, b, b};
    }
#pragma unroll
    for (int ks = 0; ks < 4; ++ks) {
        bf16x8 bfr[6];                 // batched: 6 loads in flight
#pragma unroll
        for (int j = 0; j < 6; ++j)
            bfr[j] = *(const bf16x8*)&wqkvT[(ntile[j] * 16 + col) * 128 + ks * 32 + quad * 8];
#pragma unroll
        for (int j = 0; j < 6; ++j) {  // each bfrag feeds 2 MFMAs
            acc[0][j] = __builtin_amdgcn_mfma_f32_16x16x32_bf16(afr[0][ks], bfr[j], acc[0][j], 0, 0, 0);
            acc[1][j] = __builtin_amdgcn_mfma_f32_16x16x32_bf16(afr[1][ks], bfr[j], acc[1][j], 0, 0, 0);
        }
    }

    // ---- stage B lane roles: (token, head-bit, i-half) within the wave
    const int t    = lane & 15;
    const int hbit = (lane >> 4) & 1;
    const int ih   = lane >> 5;
    const int h    = 2 * wave + hbit;           // head owned by this lane
    const float* qkvrow = us_f + t * QKV_STRIDE_F + h * 16;
    const float sl2e = 0.08838834764831845f * 1.44269504088896340f; // scale*log2(e)

    // write one 16-token half of this wave's qkv columns -> LDS fp32 [tok][ch]
    auto write_half = [&](int m) {
#pragma unroll
        for (int j = 0; j < 6; ++j)
#pragma unroll
            for (int r = 0; r < 4; ++r)
                us_f[(quad * 4 + r) * QKV_STRIDE_F + ntile[j] * 16 + col] = acc[m][j][r];
    };

    float4 kv4[4], vv4[4];   // 8 ds_read_b128 per half (q read lazily)
    auto read_half = [&]() {
#pragma unroll
        for (int c = 0; c < 4; ++c) {
            kv4[c] = ((const float4*)(qkvrow + 128))[c];
            vv4[c] = ((const float4*)(qkvrow + 256))[c];
        }
    };

    // ROLLED stage B: 4 iterations x 2 q-channels; q re-read from LDS
    // (runtime ip never indexes a private array -> no scratch).
    auto attn_half = [&](int mhalf) {
        unsigned short* orow = &us_o[(mhalf * 16 + t) * O_STRIDE + h * 16 + ih * 8];
        const float* qptr = qkvrow + ih * 8;
#pragma unroll 1
        for (int ip = 0; ip < 4; ++ip) {
            float q0 = qptr[ip * 2];       // 2 ds_read_b32, issued together
            float q1 = qptr[ip * 2 + 1];
            float ov0, ov1;
#pragma unroll
            for (int u = 0; u < 2; ++u) {
                float qs = (u ? q1 : q0) * sl2e;
                float den = 0.f, num = 0.f;
#pragma unroll
                for (int c = 0; c < 4; ++c) {
                    float e;
                    e = __builtin_amdgcn_exp2f(qs * kv4[c].x); den += e; num = fmaf(e, vv4[c].x, num);
                    e = __builtin_amdgcn_exp2f(qs * kv4[c].y); den += e; num = fmaf(e, vv4[c].y, num);
                    e = __builtin_amdgcn_exp2f(qs * kv4[c].z); den += e; num = fmaf(e, vv4[c].z, num);
                    e = __builtin_amdgcn_exp2f(qs * kv4[c].w); den += e; num = fmaf(e, vv4[c].w, num);
                }
                float o = num * __builtin_amdgcn_rcpf(den);
                if (u) ov1 = o; else ov0 = o;
            }
            *(unsigned int*)((char*)orow + ip * 4) = pkbf(ov0, ov1);
        }
    };

    // ---- barrier-free wave-private qkv pipeline (R7, reordered so the
    // lazy q reads of attn_half(0) complete before write_half(1))
    write_half(0);         // 24 ds_write_b32 (wave-owned columns only)
    read_half();           // RAW same wave: compiler lgkmcnt, in-order DS
    attn_half(0);          // reads q lazily from half-0, writes us_o half0
    write_half(1);         // after attn0's q reads (program order, same wave)
    read_half();
    attn_half(1);

    __syncthreads();       // the ONE barrier: o (all heads/waves) -> stage C

    // ---- stage C: out = o @ Wproj + b. Wave: 2 n-tiles x 2 m-tiles.
    const int nb2 = wave * 2;
#pragma unroll
    for (int m = 0; m < 2; ++m) {
        bf16x8 af[4];
#pragma unroll
        for (int ks = 0; ks < 4; ++ks)
            af[ks] = *(const bf16x8*)&us_o[(m * 16 + col) * O_STRIDE + ks * 32 + quad * 8];
        f32x4 acc2[2];
#pragma unroll
        for (int n = 0; n < 2; ++n) {
            float b = bproj[(nb2 + n) * 16 + col];
            acc2[n] = (f32x4){b, b, b, b};
        }
#pragma unroll
        for (int ks = 0; ks < 4; ++ks) {
            bf16x8 bb[2];
#pragma unroll
            for (int n = 0; n < 2; ++n)
                bb[n] = *(const bf16x8*)&wprojT[((nb2 + n) * 16 + col) * 128 + ks * 32 + quad * 8];
#pragma unroll
            for (int n = 0; n < 2; ++n)
                acc2[n] = __builtin_amdgcn_mfma_f32_16x16x32_bf16(af[ks], bb[n], acc2[n], 0, 0, 0);
        }
#pragma unroll
        for (int n = 0; n < 2; ++n)
#pragma unroll
            for (int r = 0; r < 4; ++r) {
                long tt = base_tok + m * 16 + quad * 4 + r;
                out[tt * 128 + (nb2 + n) * 16 + col] = acc2[n][r];
            }
    }
}

extern "C" void kernel_launch(void* const* d_in, const int* in_sizes, int n_in,
                              void* d_out, int out_size, void* d_ws, size_t ws_size,
                              hipStream_t stream) {
    const float* x     = (const float*)d_in[0];
    const float* wqkv  = (const float*)d_in[1];
    const float* bqkv  = (const float*)d_in[2];
    const float* wproj = (const float*)d_in[3];
    const float* bproj = (const float*)d_in[4];
    float* out = (float*)d_out;

    unsigned short* wqkvT  = (unsigned short*)d_ws;    // 384*128 bf16
    unsigned short* wprojT = wqkvT + 384 * 128;        // 128*128 bf16

    prep_weights<<<192, 256, 0, stream>>>(wqkv, wproj, wqkvT, wprojT);

    const int tokens = in_sizes[0] / 128;              // 65536
    fused_channel_attn<<<tokens / TILE_M, 256, 0, stream>>>(
        x, wqkvT, bqkv, wprojT, bproj, out);
}